// Round 4
// baseline (9808.414 us; speedup 1.0000x reference)
//
#include <hip/hip_runtime.h>
#include <math.h>

#define Bb 64
#define Tt 2048
#define Ii 256
#define Hh 512
#define Oo 256

#define WL_BYTES 65536   // 8 waves x 8 frags (kt14,15 x u0..3) x 1KB

using f32x4   = __attribute__((ext_vector_type(4))) float;
using bf16x8  = __attribute__((ext_vector_type(8))) short;
using u32x4   = __attribute__((ext_vector_type(4))) unsigned int;

__device__ __forceinline__ unsigned short f2bf(float f) {
    union { float f; unsigned u; } v; v.f = f;
    unsigned r = v.u + 0x7fffu + ((v.u >> 16) & 1u);
    return (unsigned short)(r >> 16);
}
__device__ __forceinline__ float bf2f(unsigned short b) {
    union { unsigned u; float f; } v; v.u = ((unsigned)b) << 16;
    return v.f;
}
__device__ __forceinline__ float tanh_fast(float x) {
    float e = __expf(x + x);
    return 1.0f - 2.0f * __builtin_amdgcn_rcpf(e + 1.0f);
}
__device__ __forceinline__ unsigned cvt_pk(float lo, float hi) {
    unsigned r;
    asm volatile("v_cvt_pk_bf16_f32 %0, %1, %2" : "=v"(r) : "v"(lo), "v"(hi));
    return r;
}
__device__ __forceinline__ void cvt16(unsigned short* dst, const float* s) {
    u32x4 a, b;
#pragma unroll
    for (int i = 0; i < 4; ++i)
        a[i] = (unsigned)f2bf(s[2*i]) | ((unsigned)f2bf(s[2*i+1]) << 16);
#pragma unroll
    for (int i = 0; i < 4; ++i)
        b[i] = (unsigned)f2bf(s[8+2*i]) | ((unsigned)f2bf(s[8+2*i+1]) << 16);
    *(u32x4*)dst = a;
    *(u32x4*)(dst + 8) = b;
}

// One MFMA A-fragment of W_hh (row = output col j, k = input col), bf16.
__device__ __forceinline__ bf16x8 w_frag(const float* __restrict__ W,
                                         int row, int kt, int lhi) {
    const float* p = W + (size_t)row * Hh + kt*32 + lhi*8;
    float s[8];
    *(f32x4*)&s[0] = *(const f32x4*)p;
    *(f32x4*)&s[4] = *(const f32x4*)(p + 4);
    bf16x8 v;
#pragma unroll
    for (int i = 0; i < 8; ++i) v[i] = (short)f2bf(s[i]);
    return v;
}

// ---------------- Phase 0: pack W_hh kt9..13 frags (bf16) into d_out scratch.
// Layout: [wv 0..7][f 0..19][lane 0..63] x 16B, f -> kt=9+(f>>2), u=f&3.
__global__ __launch_bounds__(256) void k_wprep(
    const float* __restrict__ W_hh, unsigned short* __restrict__ wfr)
{
    int idx = blockIdx.x * 256 + threadIdx.x;
    if (idx >= 8 * 20 * 64) return;
    int lane = idx & 63;
    int f = (idx >> 6) % 20;
    int wv = idx / (20 * 64);
    int kt = 9 + (f >> 2), u = f & 3;
    int l15 = lane & 15, lhi = lane >> 4;
    bf16x8 v = w_frag(W_hh, wv*64 + u*16 + l15, kt, lhi);
    *(bf16x8*)(wfr + (size_t)idx * 8) = v;
}

// ---------------- Phase 1: xp = x@W_ih^T + b_ih + b_hh, stored in k_rnn's
// per-thread (512-thread) fragment layout, in-place region (t,g) of buf -----
__global__ __launch_bounds__(256) void k_xproj(
    const float* __restrict__ x, const float* __restrict__ W_ih,
    const float* __restrict__ b_ih, const float* __restrict__ b_hh,
    unsigned short* __restrict__ buf)
{
    __shared__ __align__(16) unsigned short Asm[128][40];
    __shared__ __align__(16) unsigned short Bsm[128][40];
    __shared__ float bias_s[128];

    const int tid = threadIdx.x;
    const int lane = tid & 63, wv = tid >> 6;
    const int l15 = lane & 15, lhi = lane >> 4;
    const int r0 = blockIdx.x * 128, c0 = blockIdx.y * 128;

    if (tid < 128) { int c = c0 + tid; bias_s[tid] = b_ih[c] + b_hh[c]; }

    const int srow = tid >> 1, sks = (tid & 1) * 16;
    const int Rr = r0 + srow;
    const float* asrc = x + ((size_t)(Rr & 63) * Tt + (Rr >> 6)) * Ii + sks;
    const float* bsrc = W_ih + (size_t)(c0 + srow) * Ii + sks;

    const int m0 = (wv >> 1) * 64, n0 = (wv & 1) * 64;

    f32x4 acc[4][4];
#pragma unroll
    for (int i = 0; i < 4; ++i)
#pragma unroll
        for (int j = 0; j < 4; ++j) acc[i][j] = (f32x4){0.f,0.f,0.f,0.f};

    for (int kk = 0; kk < Ii/32; ++kk) {
        __syncthreads();
        {
            float s[16];
#pragma unroll
            for (int q = 0; q < 4; ++q) *(f32x4*)&s[q*4] = *(const f32x4*)(asrc + kk*32 + q*4);
            cvt16(&Asm[srow][sks], s);
#pragma unroll
            for (int q = 0; q < 4; ++q) *(f32x4*)&s[q*4] = *(const f32x4*)(bsrc + kk*32 + q*4);
            cvt16(&Bsm[srow][sks], s);
        }
        __syncthreads();
        bf16x8 af[4], bfr[4];
#pragma unroll
        for (int mi = 0; mi < 4; ++mi) af[mi]  = *(const bf16x8*)&Asm[m0 + mi*16 + l15][lhi*8];
#pragma unroll
        for (int ni = 0; ni < 4; ++ni) bfr[ni] = *(const bf16x8*)&Bsm[n0 + ni*16 + l15][lhi*8];
#pragma unroll
        for (int mi = 0; mi < 4; ++mi)
#pragma unroll
            for (int ni = 0; ni < 4; ++ni)
                acc[mi][ni] = __builtin_amdgcn_mfma_f32_16x16x32_bf16(af[mi], bfr[ni], acc[mi][ni], 0, 0, 0);
    }
    // Epilogue: element (R=t*64+b, c) -> k_rnn fragment address.
#pragma unroll
    for (int mi = 0; mi < 4; ++mi)
#pragma unroll
        for (int ni = 0; ni < 4; ++ni) {
            int n = n0 + ni*16 + l15;
            int c = c0 + n;
            float bias = bias_s[n];
            int wv2 = c >> 6, u2 = (c >> 4) & 3, lhi2 = (c >> 2) & 3, ri2 = c & 3;
#pragma unroll
            for (int ri = 0; ri < 4; ++ri) {
                int m = m0 + mi*16 + lhi*4 + ri;
                int R = r0 + m;
                int tt2 = R >> 6, b = R & 63;
                int tid2 = wv2*64 + lhi2*16 + (b & 15);
                size_t addr = ((size_t)tt2*4 + (b >> 4)) * 8192
                            + (size_t)tid2 * 16 + u2*4 + ri2;
                buf[addr] = f2bf(acc[mi][ni][ri] + bias);
            }
        }
}

// ---------------- Phase 2: recurrence, 4 blocks x 512 threads --------------
// 8 waves (2/SIMD). Per wave (64 j-cols): W kt0-8 in regs (36 frags),
// kt9-13 streamed from L2 (packed frag buffer), kt14-15 in LDS.
// h double-buffered in LDS -> ONE raw barrier per step, no vmcnt drain.
__global__ __launch_bounds__(512, 2) void k_rnn(
    const float* __restrict__ W_hh, unsigned short* buf,
    const unsigned short* __restrict__ wfr)
{
    __shared__ __align__(16) char smem[WL_BYTES + 32768];
    char* wl  = smem;
    char* hs0 = smem + WL_BYTES;
    char* hs1 = hs0 + 16384;

    const int tid = threadIdx.x;
    const int lane = tid & 63, wv = tid >> 6;
    const int l15 = lane & 15, lhi = lane >> 4;
    const int g = blockIdx.x;
    const int swz = (l15 & 7) << 4;

    // ---- persistent W reg-frags: kt0..8
    bf16x8 WR[36];
#pragma unroll
    for (int kt = 0; kt < 9; ++kt)
#pragma unroll
        for (int u = 0; u < 4; ++u)
            WR[kt*4 + u] = w_frag(W_hh, wv*64 + u*16 + l15, kt, lhi);

    // ---- LDS W-frags: kt14,15
    char* wbase = wl + wv * 8192 + lane * 16;
#pragma unroll
    for (int kt = 14; kt < 16; ++kt)
#pragma unroll
        for (int u = 0; u < 4; ++u)
            *(bf16x8*)(wbase + (size_t)((kt-14)*4 + u) * 1024)
                = w_frag(W_hh, wv*64 + u*16 + l15, kt, lhi);
    __syncthreads();

    // ---- L2-streamed W-frags base (kt9..13)
    const char* gw = (const char*)wfr + (size_t)wv * 20480 + (size_t)lane * 16;

#define PREF(A0, A1, TP_) do { \
    const u32x4* pp = (const u32x4*)((const char*)buf \
        + ((size_t)(TP_)*4 + g) * 16384 + (size_t)tid * 32); \
    A0 = pp[0]; A1 = pp[1]; \
  } while (0)

#define EPI(T_, HS_, X0, X1) do { \
    unsigned short* orow = buf + ((size_t)(T_)*64 + g*16 + l15) * Hh \
                         + (wv << 6) + (lhi << 2); \
    _Pragma("unroll") \
    for (int u = 0; u < 4; ++u) { \
        const u32x4 xv = (u < 2) ? X0 : X1; \
        float z[4]; \
        _Pragma("unroll") \
        for (int r = 0; r < 4; ++r) { \
            unsigned w = xv[(u & 1) * 2 + (r >> 1)]; \
            float xf = __uint_as_float((r & 1) ? (w & 0xffff0000u) : (w << 16)); \
            z[r] = acc[u][r] + xf; \
        } \
        uint2 pk; \
        pk.x = cvt_pk(tanh_fast(z[0]), tanh_fast(z[1])); \
        pk.y = cvt_pk(tanh_fast(z[2]), tanh_fast(z[3])); \
        int byt = (l15 << 10) + (wv << 7) + (u << 5) + (lhi << 3); \
        *(uint2*)((HS_) + (byt ^ swz)) = pk; \
        *(uint2*)(orow + (u << 4)) = pk; \
    } \
  } while (0)

#define STEP(T_, RB_, WB_, XU0, XU1, XP0, XP1, TP_) do { \
    PREF(XP0, XP1, TP_); \
    f32x4 acc[4]; \
    acc[0] = acc[1] = acc[2] = acc[3] = (f32x4){0.f, 0.f, 0.f, 0.f}; \
    __builtin_amdgcn_s_setprio(1); \
    _Pragma("unroll") \
    for (int kt = 0; kt < 16; ++kt) { \
        int byt = (l15 << 10) + (kt << 6) + (lhi << 4); \
        bf16x8 hf = *(const bf16x8*)((RB_) + (byt ^ swz)); \
        _Pragma("unroll") \
        for (int u = 0; u < 4; ++u) { \
            bf16x8 a; \
            if (kt < 9)       a = WR[kt*4 + u]; \
            else if (kt < 14) a = *(const bf16x8*)(gw + (size_t)(((kt-9)*4 + u) << 10)); \
            else              a = *(const bf16x8*)(wbase + (size_t)(((kt-14)*4 + u) << 10)); \
            acc[u] = __builtin_amdgcn_mfma_f32_16x16x32_bf16(a, hf, acc[u], 0, 0, 0); \
        } \
    } \
    __builtin_amdgcn_s_setprio(0); \
    EPI(T_, WB_, XU0, XU1); \
    asm volatile("" :: "v"(XP0[0]), "v"(XP1[0]));  /* xp(t+1) landed pre-barrier */ \
    asm volatile("s_waitcnt lgkmcnt(0)" ::: "memory"); \
    __builtin_amdgcn_s_barrier(); \
  } while (0)

    u32x4 xa0, xa1, xb0, xb1;
    PREF(xa0, xa1, 0);
    PREF(xb0, xb1, 1);

    {   // t = 0: h0 = tanh(xp0); extra barrier guards in-place overwrite of xp(0)
        f32x4 acc[4];
        acc[0] = acc[1] = acc[2] = acc[3] = (f32x4){0.f, 0.f, 0.f, 0.f};
        asm volatile("" :: "v"(xa0[0]), "v"(xa1[0]), "v"(xb0[0]), "v"(xb1[0]));
        __syncthreads();
        EPI(0, hs0, xa0, xa1);
        asm volatile("s_waitcnt lgkmcnt(0)" ::: "memory");
        __builtin_amdgcn_s_barrier();
    }

#pragma unroll 1
    for (int t = 1; t < Tt - 1; t += 2) {
        STEP(t,     hs0, hs1, xb0, xb1, xa0, xa1, t + 1);
        STEP(t + 1, hs1, hs0, xa0, xa1, xb0, xb1, (t + 2 < Tt ? t + 2 : Tt - 1));
    }
    STEP(Tt - 1, hs0, hs1, xb0, xb1, xa0, xa1, Tt - 1);   // dummy prefetch

#undef PREF
#undef EPI
#undef STEP
}

// ---------------- Phase 3: out[b*T+t][o] = outs[t,b,:]·W_fc[o,:] + b_fc -----
__global__ __launch_bounds__(256) void k_fc(
    const unsigned short* __restrict__ buf, const float* __restrict__ W_fc,
    const float* __restrict__ b_fc, float* __restrict__ out)
{
    __shared__ __align__(16) unsigned short Asm[128][40];
    __shared__ __align__(16) unsigned short Bsm[128][40];
    __shared__ float bias_s[128];

    const int tid = threadIdx.x;
    const int lane = tid & 63, wv = tid >> 6;
    const int l15 = lane & 15, lhi = lane >> 4;
    const int r0 = blockIdx.x * 128, c0 = blockIdx.y * 128;

    if (tid < 128) bias_s[tid] = b_fc[c0 + tid];

    const int srow = tid >> 1, sks = (tid & 1) * 16;
    const unsigned short* asrc = buf + (size_t)(r0 + srow) * Hh + sks;
    const float* bsrc = W_fc + (size_t)(c0 + srow) * Hh + sks;

    const int m0 = (wv >> 1) * 64, n0 = (wv & 1) * 64;

    f32x4 acc[4][4];
#pragma unroll
    for (int i = 0; i < 4; ++i)
#pragma unroll
        for (int j = 0; j < 4; ++j) acc[i][j] = (f32x4){0.f,0.f,0.f,0.f};

    for (int kk = 0; kk < Hh/32; ++kk) {
        __syncthreads();
        {
            const unsigned short* pa = asrc + kk*32;
            *(u32x4*)&Asm[srow][sks]     = *(const u32x4*)pa;
            *(u32x4*)&Asm[srow][sks + 8] = *(const u32x4*)(pa + 8);
            float s[16];
#pragma unroll
            for (int q = 0; q < 4; ++q) *(f32x4*)&s[q*4] = *(const f32x4*)(bsrc + kk*32 + q*4);
            cvt16(&Bsm[srow][sks], s);
        }
        __syncthreads();
        bf16x8 af[4], bfr[4];
#pragma unroll
        for (int mi = 0; mi < 4; ++mi) af[mi]  = *(const bf16x8*)&Asm[m0 + mi*16 + l15][lhi*8];
#pragma unroll
        for (int ni = 0; ni < 4; ++ni) bfr[ni] = *(const bf16x8*)&Bsm[n0 + ni*16 + l15][lhi*8];
#pragma unroll
        for (int mi = 0; mi < 4; ++mi)
#pragma unroll
            for (int ni = 0; ni < 4; ++ni)
                acc[mi][ni] = __builtin_amdgcn_mfma_f32_16x16x32_bf16(af[mi], bfr[ni], acc[mi][ni], 0, 0, 0);
    }
#pragma unroll
    for (int mi = 0; mi < 4; ++mi)
#pragma unroll
        for (int ni = 0; ni < 4; ++ni) {
            int n = n0 + ni*16 + l15;
            float bias = bias_s[n];
#pragma unroll
            for (int ri = 0; ri < 4; ++ri) {
                int m = m0 + mi*16 + lhi*4 + ri;
                int R = r0 + m;                         // buf row = t*64+b
                int bb = R & 63, tt = R >> 6;
                out[((size_t)bb * Tt + tt) * Oo + (c0 + n)] = acc[mi][ni][ri] + bias;
            }
        }
}

// ---------------- Phase 4: hidden = h_{T-1} --------------------------------
__global__ void k_hid(const unsigned short* __restrict__ buf, float* __restrict__ hid) {
    int i = blockIdx.x * blockDim.x + threadIdx.x;
    if (i < Bb * Hh) {
        int b = i >> 9, j = i & 511;
        hid[i] = bf2f(buf[((size_t)(Tt - 1) * Bb + b) * Hh + j]);
    }
}

extern "C" void kernel_launch(void* const* d_in, const int* in_sizes, int n_in,
                              void* d_out, int out_size, void* d_ws, size_t ws_size,
                              hipStream_t stream) {
    (void)in_sizes; (void)n_in; (void)out_size; (void)ws_size;
    const float* x    = (const float*)d_in[0];
    const float* W_ih = (const float*)d_in[1];
    const float* W_hh = (const float*)d_in[2];
    const float* b_ih = (const float*)d_in[3];
    const float* b_hh = (const float*)d_in[4];
    const float* W_fc = (const float*)d_in[5];
    const float* b_fc = (const float*)d_in[6];
    float* out = (float*)d_out;

    unsigned short* buf = (unsigned short*)d_ws;   // [T*B][H] bf16: xp(frag) -> h (in place)
    // W kt9-13 frag buffer (160 KB) lives in d_out's main region: dead until
    // k_fc overwrites it, which happens after k_rnn on the same stream.
    unsigned short* wfr = (unsigned short*)d_out;

    k_wprep<<<dim3(40),       dim3(256), 0, stream>>>(W_hh, wfr);
    k_xproj<<<dim3(1024, 4),  dim3(256), 0, stream>>>(x, W_ih, b_ih, b_hh, buf);
    k_rnn  <<<dim3(4),        dim3(512), 0, stream>>>(W_hh, buf, wfr);
    k_fc   <<<dim3(1024, 2),  dim3(256), 0, stream>>>(buf, W_fc, b_fc, out);
    k_hid  <<<dim3(64),       dim3(512), 0, stream>>>(buf, out + (size_t)Bb * Tt * Oo);
}

// Round 5
// 5920.249 us; speedup vs baseline: 1.6568x; 1.6568x over previous
//
#include <hip/hip_runtime.h>
#include <math.h>

#define Bb 64
#define Tt 2048
#define Ii 256
#define Hh 512
#define Oo 256

using f32x4   = __attribute__((ext_vector_type(4))) float;
using bf16x8  = __attribute__((ext_vector_type(8))) short;
using u32x4   = __attribute__((ext_vector_type(4))) unsigned int;

__device__ __forceinline__ unsigned short f2bf(float f) {
    union { float f; unsigned u; } v; v.f = f;
    unsigned r = v.u + 0x7fffu + ((v.u >> 16) & 1u);
    return (unsigned short)(r >> 16);
}
__device__ __forceinline__ float tanh_fast(float x) {
    float e = __expf(x + x);
    return 1.0f - 2.0f * __builtin_amdgcn_rcpf(e + 1.0f);
}
__device__ __forceinline__ unsigned cvt_pk(float lo, float hi) {
    unsigned r;
    asm volatile("v_cvt_pk_bf16_f32 %0, %1, %2" : "=v"(r) : "v"(lo), "v"(hi));
    return r;
}
__device__ __forceinline__ void cvt16(unsigned short* dst, const float* s) {
    u32x4 a, b;
#pragma unroll
    for (int i = 0; i < 4; ++i)
        a[i] = (unsigned)f2bf(s[2*i]) | ((unsigned)f2bf(s[2*i+1]) << 16);
#pragma unroll
    for (int i = 0; i < 4; ++i)
        b[i] = (unsigned)f2bf(s[8+2*i]) | ((unsigned)f2bf(s[8+2*i+1]) << 16);
    *(u32x4*)dst = a;
    *(u32x4*)(dst + 8) = b;
}

// One MFMA A-fragment of W_hh (row = output col j, k = input col), bf16.
__device__ __forceinline__ bf16x8 w_frag(const float* __restrict__ W,
                                         int row, int kt, int lhi) {
    const float* p = W + (size_t)row * Hh + kt*32 + lhi*8;
    float s[8];
    *(f32x4*)&s[0] = *(const f32x4*)p;
    *(f32x4*)&s[4] = *(const f32x4*)(p + 4);
    bf16x8 v;
#pragma unroll
    for (int i = 0; i < 8; ++i) v[i] = (short)f2bf(s[i]);
    return v;
}

// ---------------- Phase 1: xp = x@W_ih^T + b_ih + b_hh, stored in k_rnn's
// per-thread (512-thread) fragment layout, in-place region (t,g) of buf -----
__global__ __launch_bounds__(256) void k_xproj(
    const float* __restrict__ x, const float* __restrict__ W_ih,
    const float* __restrict__ b_ih, const float* __restrict__ b_hh,
    unsigned short* __restrict__ buf)
{
    __shared__ __align__(16) unsigned short Asm[128][40];
    __shared__ __align__(16) unsigned short Bsm[128][40];
    __shared__ float bias_s[128];

    const int tid = threadIdx.x;
    const int lane = tid & 63, wv = tid >> 6;
    const int l15 = lane & 15, lhi = lane >> 4;
    const int r0 = blockIdx.x * 128, c0 = blockIdx.y * 128;

    if (tid < 128) { int c = c0 + tid; bias_s[tid] = b_ih[c] + b_hh[c]; }

    const int srow = tid >> 1, sks = (tid & 1) * 16;
    const int Rr = r0 + srow;
    const float* asrc = x + ((size_t)(Rr & 63) * Tt + (Rr >> 6)) * Ii + sks;
    const float* bsrc = W_ih + (size_t)(c0 + srow) * Ii + sks;

    const int m0 = (wv >> 1) * 64, n0 = (wv & 1) * 64;

    f32x4 acc[4][4];
#pragma unroll
    for (int i = 0; i < 4; ++i)
#pragma unroll
        for (int j = 0; j < 4; ++j) acc[i][j] = (f32x4){0.f,0.f,0.f,0.f};

    for (int kk = 0; kk < Ii/32; ++kk) {
        __syncthreads();
        {
            float s[16];
#pragma unroll
            for (int q = 0; q < 4; ++q) *(f32x4*)&s[q*4] = *(const f32x4*)(asrc + kk*32 + q*4);
            cvt16(&Asm[srow][sks], s);
#pragma unroll
            for (int q = 0; q < 4; ++q) *(f32x4*)&s[q*4] = *(const f32x4*)(bsrc + kk*32 + q*4);
            cvt16(&Bsm[srow][sks], s);
        }
        __syncthreads();
        bf16x8 af[4], bfr[4];
#pragma unroll
        for (int mi = 0; mi < 4; ++mi) af[mi]  = *(const bf16x8*)&Asm[m0 + mi*16 + l15][lhi*8];
#pragma unroll
        for (int ni = 0; ni < 4; ++ni) bfr[ni] = *(const bf16x8*)&Bsm[n0 + ni*16 + l15][lhi*8];
#pragma unroll
        for (int mi = 0; mi < 4; ++mi)
#pragma unroll
            for (int ni = 0; ni < 4; ++ni)
                acc[mi][ni] = __builtin_amdgcn_mfma_f32_16x16x32_bf16(af[mi], bfr[ni], acc[mi][ni], 0, 0, 0);
    }
    // Epilogue: element (R=t*64+b, c) -> k_rnn fragment address.
#pragma unroll
    for (int mi = 0; mi < 4; ++mi)
#pragma unroll
        for (int ni = 0; ni < 4; ++ni) {
            int n = n0 + ni*16 + l15;
            int c = c0 + n;
            float bias = bias_s[n];
            int wv2 = c >> 6, u2 = (c >> 4) & 3, lhi2 = (c >> 2) & 3, ri2 = c & 3;
#pragma unroll
            for (int ri = 0; ri < 4; ++ri) {
                int m = m0 + mi*16 + lhi*4 + ri;
                int R = r0 + m;
                int tt2 = R >> 6, b = R & 63;
                int tid2 = wv2*64 + lhi2*16 + (b & 15);
                size_t addr = ((size_t)tt2*4 + (b >> 4)) * 8192
                            + (size_t)tid2 * 16 + u2*4 + ri2;
                buf[addr] = f2bf(acc[mi][ni][ri] + bias);
            }
        }
}

// ---------------- Phase 2: recurrence, 4 blocks x 512 threads --------------
// 8 waves (2/SIMD). Per wave (64 j-cols): W u0-2 (48 frags) in regs,
// u3 (16 frags) in LDS. Hand-pipelined ds_reads: hf 4-deep, W-LDS 3-deep.
// Raw barriers (lgkm drain only); vmcnt never drained to 0.
__global__ __launch_bounds__(512, 2) void k_rnn(
    const float* __restrict__ W_hh, unsigned short* buf)
{
    __shared__ __align__(16) char smem[147456];
    char* wl = smem;            // 8 waves x 16 frags x 1KB = 128KB
    char* hs = smem + 131072;   // h [16 batch][512 j] bf16, XOR-swz, 16KB

    const int tid = threadIdx.x;
    const int lane = tid & 63, wv = tid >> 6;
    const int l15 = lane & 15, lhi = lane >> 4;
    const int g = blockIdx.x;
    const int swz = (l15 & 7) << 4;

    // ---- persistent W reg-frags: u = 0..2, all 16 kt
    bf16x8 WR[48];
#pragma unroll
    for (int kt = 0; kt < 16; ++kt)
#pragma unroll
        for (int u = 0; u < 3; ++u)
            WR[kt*3 + u] = w_frag(W_hh, wv*64 + u*16 + l15, kt, lhi);

    // ---- LDS W-frags: u = 3, all 16 kt
    char* wlb = wl + wv * 16384 + lane * 16;
#pragma unroll
    for (int kt = 0; kt < 16; ++kt)
        *(bf16x8*)(wlb + (kt << 10)) = w_frag(W_hh, wv*64 + 48 + l15, kt, lhi);

    u32x4 xpc0, xpc1;   // current step's xp (32B/thread, fragment layout)

#define PREF(TP_) do { \
    const u32x4* pp = (const u32x4*)((const char*)buf \
        + ((size_t)(TP_)*4 + g) * 16384 + (size_t)tid * 32); \
    xpc0 = pp[0]; xpc1 = pp[1]; \
  } while (0)

#define HF(KT) (*(const bf16x8*)(hs + ((((l15) << 10) + ((KT) << 6) + (lhi << 4)) ^ swz)))
#define WFL(KT) (*(const bf16x8*)(wlb + ((KT) << 10)))
#define MF(A_, B_, C_) __builtin_amdgcn_mfma_f32_16x16x32_bf16(A_, B_, C_, 0, 0, 0)

#define KQ(KT, HN, WN) \
    acc[0] = MF(WR[(KT)*3+0], HN, acc[0]); \
    acc[1] = MF(WR[(KT)*3+1], HN, acc[1]); \
    acc[2] = MF(WR[(KT)*3+2], HN, acc[2]); \
    acc[3] = MF(WN,           HN, acc[3]);

// Epilogue: z = acc + xp; reload xp for TP_; h = tanh(z) -> hs + global row.
#define EPI(T_, TP_) do { \
    float z[4][4]; \
    _Pragma("unroll") \
    for (int u = 0; u < 4; ++u) { \
        const u32x4 xv = (u < 2) ? xpc0 : xpc1; \
        _Pragma("unroll") \
        for (int r = 0; r < 4; ++r) { \
            unsigned w = xv[(u & 1) * 2 + (r >> 1)]; \
            float xf = __uint_as_float((r & 1) ? (w & 0xffff0000u) : (w << 16)); \
            z[u][r] = acc[u][r] + xf; \
        } \
    } \
    PREF(TP_); \
    unsigned short* orow = buf + ((size_t)(T_)*64 + g*16 + l15) * Hh \
                         + (wv << 6) + (lhi << 2); \
    _Pragma("unroll") \
    for (int u = 0; u < 4; ++u) { \
        uint2 pk; \
        pk.x = cvt_pk(tanh_fast(z[u][0]), tanh_fast(z[u][1])); \
        pk.y = cvt_pk(tanh_fast(z[u][2]), tanh_fast(z[u][3])); \
        int byt = (l15 << 10) + ((wv << 7) + (u << 5) + (lhi << 3)); \
        *(uint2*)(hs + (byt ^ swz)) = pk; \
        *(uint2*)(orow + (u << 4)) = pk; \
    } \
  } while (0)

#define STEP(T_, TP_) do { \
    f32x4 acc[4]; \
    acc[0] = acc[1] = acc[2] = acc[3] = (f32x4){0.f, 0.f, 0.f, 0.f}; \
    bf16x8 h0 = HF(0), h1 = HF(1), h2 = HF(2), h3 = HF(3); \
    bf16x8 w0 = WFL(0), w1 = WFL(1), w2 = WFL(2); \
    __builtin_amdgcn_s_setprio(1); \
    KQ(0,  h0, w0) h0 = HF(4);  w0 = WFL(3); \
    KQ(1,  h1, w1) h1 = HF(5);  w1 = WFL(4); \
    KQ(2,  h2, w2) h2 = HF(6);  w2 = WFL(5); \
    KQ(3,  h3, w0) h3 = HF(7);  w0 = WFL(6); \
    KQ(4,  h0, w1) h0 = HF(8);  w1 = WFL(7); \
    KQ(5,  h1, w2) h1 = HF(9);  w2 = WFL(8); \
    KQ(6,  h2, w0) h2 = HF(10); w0 = WFL(9); \
    KQ(7,  h3, w1) h3 = HF(11); w1 = WFL(10); \
    KQ(8,  h0, w2) h0 = HF(12); w2 = WFL(11); \
    KQ(9,  h1, w0) h1 = HF(13); w0 = WFL(12); \
    KQ(10, h2, w1) h2 = HF(14); w1 = WFL(13); \
    KQ(11, h3, w2) h3 = HF(15); w2 = WFL(14); \
    KQ(12, h0, w0) w0 = WFL(15); \
    KQ(13, h1, w1) \
    KQ(14, h2, w2) \
    KQ(15, h3, w0) \
    __builtin_amdgcn_s_setprio(0); \
    asm volatile("" :: "v"(xpc0[0]), "v"(xpc1[0]));  /* xp(T_) landed */ \
    asm volatile("s_waitcnt lgkmcnt(0)" ::: "memory"); \
    __builtin_amdgcn_s_barrier();   /* hs reads done; region-T_ loads done */ \
    EPI(T_, TP_); \
    asm volatile("s_waitcnt lgkmcnt(0)" ::: "memory"); \
    __builtin_amdgcn_s_barrier();   /* h_T in hs before next step reads */ \
  } while (0)

    PREF(0);

    {   // t = 0: h0 = tanh(xp0)
        f32x4 acc[4];
        acc[0] = acc[1] = acc[2] = acc[3] = (f32x4){0.f, 0.f, 0.f, 0.f};
        asm volatile("" :: "v"(xpc0[0]), "v"(xpc1[0]));
        __syncthreads();   // wl staged + all xp(0) loads complete
        EPI(0, 1);
        asm volatile("s_waitcnt lgkmcnt(0)" ::: "memory");
        __builtin_amdgcn_s_barrier();
    }

#pragma unroll 1
    for (int t = 1; t < Tt; ++t) {
        STEP(t, (t + 1 < Tt ? t + 1 : Tt - 1));   // final: dummy reload
    }

#undef PREF
#undef HF
#undef WFL
#undef MF
#undef KQ
#undef EPI
#undef STEP
}

// ---------------- Phase 3: out[b*T+t][o] = outs[t,b,:]·W_fc[o,:] + b_fc -----
__global__ __launch_bounds__(256) void k_fc(
    const unsigned short* __restrict__ buf, const float* __restrict__ W_fc,
    const float* __restrict__ b_fc, float* __restrict__ out)
{
    __shared__ __align__(16) unsigned short Asm[128][40];
    __shared__ __align__(16) unsigned short Bsm[128][40];
    __shared__ float bias_s[128];

    const int tid = threadIdx.x;
    const int lane = tid & 63, wv = tid >> 6;
    const int l15 = lane & 15, lhi = lane >> 4;
    const int r0 = blockIdx.x * 128, c0 = blockIdx.y * 128;

    if (tid < 128) bias_s[tid] = b_fc[c0 + tid];

    const int srow = tid >> 1, sks = (tid & 1) * 16;
    const unsigned short* asrc = buf + (size_t)(r0 + srow) * Hh + sks;
    const float* bsrc = W_fc + (size_t)(c0 + srow) * Hh + sks;

    const int m0 = (wv >> 1) * 64, n0 = (wv & 1) * 64;

    f32x4 acc[4][4];
#pragma unroll
    for (int i = 0; i < 4; ++i)
#pragma unroll
        for (int j = 0; j < 4; ++j) acc[i][j] = (f32x4){0.f,0.f,0.f,0.f};

    for (int kk = 0; kk < Hh/32; ++kk) {
        __syncthreads();
        {
            const unsigned short* pa = asrc + kk*32;
            *(u32x4*)&Asm[srow][sks]     = *(const u32x4*)pa;
            *(u32x4*)&Asm[srow][sks + 8] = *(const u32x4*)(pa + 8);
            float s[16];
#pragma unroll
            for (int q = 0; q < 4; ++q) *(f32x4*)&s[q*4] = *(const f32x4*)(bsrc + kk*32 + q*4);
            cvt16(&Bsm[srow][sks], s);
        }
        __syncthreads();
        bf16x8 af[4], bfr[4];
#pragma unroll
        for (int mi = 0; mi < 4; ++mi) af[mi]  = *(const bf16x8*)&Asm[m0 + mi*16 + l15][lhi*8];
#pragma unroll
        for (int ni = 0; ni < 4; ++ni) bfr[ni] = *(const bf16x8*)&Bsm[n0 + ni*16 + l15][lhi*8];
#pragma unroll
        for (int mi = 0; mi < 4; ++mi)
#pragma unroll
            for (int ni = 0; ni < 4; ++ni)
                acc[mi][ni] = __builtin_amdgcn_mfma_f32_16x16x32_bf16(af[mi], bfr[ni], acc[mi][ni], 0, 0, 0);
    }
#pragma unroll
    for (int mi = 0; mi < 4; ++mi)
#pragma unroll
        for (int ni = 0; ni < 4; ++ni) {
            int n = n0 + ni*16 + l15;
            float bias = bias_s[n];
#pragma unroll
            for (int ri = 0; ri < 4; ++ri) {
                int m = m0 + mi*16 + lhi*4 + ri;
                int R = r0 + m;                         // buf row = t*64+b
                int bb = R & 63, tt = R >> 6;
                out[((size_t)bb * Tt + tt) * Oo + (c0 + n)] = acc[mi][ni][ri] + bias;
            }
        }
}

// ---------------- Phase 4: hidden = h_{T-1} --------------------------------
__global__ void k_hid(const unsigned short* __restrict__ buf, float* __restrict__ hid) {
    int i = blockIdx.x * blockDim.x + threadIdx.x;
    if (i < Bb * Hh) {
        int b = i >> 9, j = i & 511;
        union { unsigned u; float f; } v;
        v.u = ((unsigned)buf[((size_t)(Tt - 1) * Bb + b) * Hh + j]) << 16;
        hid[i] = v.f;
    }
}

extern "C" void kernel_launch(void* const* d_in, const int* in_sizes, int n_in,
                              void* d_out, int out_size, void* d_ws, size_t ws_size,
                              hipStream_t stream) {
    (void)in_sizes; (void)n_in; (void)out_size; (void)ws_size;
    const float* x    = (const float*)d_in[0];
    const float* W_ih = (const float*)d_in[1];
    const float* W_hh = (const float*)d_in[2];
    const float* b_ih = (const float*)d_in[3];
    const float* b_hh = (const float*)d_in[4];
    const float* W_fc = (const float*)d_in[5];
    const float* b_fc = (const float*)d_in[6];
    float* out = (float*)d_out;

    unsigned short* buf = (unsigned short*)d_ws;  // [T*B][H] bf16: xp(frag) -> h (in place)

    k_xproj<<<dim3(1024, 4),  dim3(256), 0, stream>>>(x, W_ih, b_ih, b_hh, buf);
    k_rnn  <<<dim3(4),        dim3(512), 0, stream>>>(W_hh, buf);
    k_fc   <<<dim3(1024, 2),  dim3(256), 0, stream>>>(buf, W_fc, b_fc, out);
    k_hid  <<<dim3(64),       dim3(512), 0, stream>>>(buf, out + (size_t)Bb * Tt * Oo);
}